// Round 1
// 1030.392 us; speedup vs baseline: 1.1803x; 1.1803x over previous
//
#include <hip/hip_runtime.h>

#define N_USERS 100000
#define N_ITEMS 200000
#define N_NODES (N_USERS + N_ITEMS)
#define EMB     64
#define NNZ     4000000

#define SCAN_BLOCK 256
#define SCAN_ITEMS 4
#define SCAN_TILE  (SCAN_BLOCK * SCAN_ITEMS)               // 1024
#define NUM_TILES  ((N_NODES + SCAN_TILE - 1) / SCAN_TILE) // 293

// coarse row-buckets: 1024 rows each -> runs in pass-1 are ~14 edges (~112B)
#define BSHIFT 10
#define BROWS  (1 << BSHIFT)                               // 1024 rows / bucket
#define NBUCK  ((N_NODES + BROWS - 1) >> BSHIFT)           // 293

// block-aggregated binning pass
#define AGG_THR    512
#define AGG_EPT    8
#define AGG_T      (AGG_THR * AGG_EPT)                     // 4096 edges / block
#define AGG_BLOCKS ((NNZ + AGG_T - 1) / AGG_T)             // 977
#define SCAN_N     512                                     // pow2 >= NBUCK

// ===========================================================================
// CSR build
// ===========================================================================
__global__ void hist_kernel(const int* __restrict__ rows, int* __restrict__ cnt) {
    int e = blockIdx.x * blockDim.x + threadIdx.x;
    if (e < NNZ) atomicAdd(&cnt[rows[e]], 1);
}

__global__ void scan1_kernel(const int* __restrict__ cnt,
                             int* __restrict__ excl,
                             int* __restrict__ tile_sums) {
    __shared__ int s[SCAN_BLOCK];
    int tid  = threadIdx.x;
    int base = blockIdx.x * SCAN_TILE + tid * SCAN_ITEMS;
    int v[SCAN_ITEMS];
    int sum = 0;
#pragma unroll
    for (int j = 0; j < SCAN_ITEMS; j++) {
        int idx = base + j;
        v[j] = (idx < N_NODES) ? cnt[idx] : 0;
        sum += v[j];
    }
    s[tid] = sum;
    __syncthreads();
    for (int off = 1; off < SCAN_BLOCK; off <<= 1) {
        int t = 0;
        if (tid >= off) t = s[tid - off];
        __syncthreads();
        if (tid >= off) s[tid] += t;
        __syncthreads();
    }
    int run = s[tid] - sum;
#pragma unroll
    for (int j = 0; j < SCAN_ITEMS; j++) {
        int idx = base + j;
        if (idx < N_NODES) excl[idx] = run;
        run += v[j];
    }
    if (tid == SCAN_BLOCK - 1) tile_sums[blockIdx.x] = s[tid];
}

__global__ void scan2_kernel(int* __restrict__ tile_sums) {
    __shared__ int s[512];
    int tid = threadIdx.x;
    int v = (tid < NUM_TILES) ? tile_sums[tid] : 0;
    s[tid] = v;
    __syncthreads();
    for (int off = 1; off < 512; off <<= 1) {
        int t = 0;
        if (tid >= off) t = s[tid - off];
        __syncthreads();
        if (tid >= off) s[tid] += t;
        __syncthreads();
    }
    if (tid < NUM_TILES) tile_sums[tid] = s[tid] - v;
}

__global__ void scan3_kernel(int* __restrict__ row_ptr,
                             const int* __restrict__ tile_sums,
                             int* __restrict__ cursor) {
    int i = blockIdx.x * blockDim.x + threadIdx.x;
    if (i < N_NODES) {
        int v = row_ptr[i] + tile_sums[i / SCAN_TILE];
        row_ptr[i] = v;
        cursor[i]  = v;
    }
    if (i == 0) row_ptr[N_NODES] = NNZ;
}

// bucket cursors (64B-padded) = CSR offset of bucket start
__global__ void binit_kernel(const int* __restrict__ row_ptr, int* __restrict__ bcur) {
    int b = blockIdx.x * blockDim.x + threadIdx.x;
    if (b < NBUCK) bcur[b * 16] = row_ptr[b << BSHIFT];
}

// pass 1 (block-aggregated): bin 4096 edges/block into coarse buckets via LDS
// counting-sort, reserve each bucket's run with ONE global atomic per
// (block,bucket), write runs contiguously & coalesced. rlo is packed into the
// high bits of the col field (col < 2^19, rlo 10 bits).
__global__ __launch_bounds__(AGG_THR)
void bucket_agg_kernel(const int*   __restrict__ rows,
                       const int*   __restrict__ cols,
                       const float* __restrict__ vals,
                       int*         __restrict__ bcur,
                       float2*      __restrict__ pay) {
    __shared__ int            cntS[SCAN_N];   // counts -> exclusive scan
    __shared__ int            hoff[SCAN_N];   // global run start per bucket
    __shared__ float2         payS[AGG_T];    // staged (packed col, val)
    __shared__ unsigned short bidS[AGG_T];    // bucket id per staged slot

    int tid  = threadIdx.x;
    int base = blockIdx.x * AGG_T;

    for (int i = tid; i < SCAN_N; i += AGG_THR) cntS[i] = 0;
    __syncthreads();

    // phase A: count (keep per-edge bucket/row-lo/local-pos packed in regs)
    unsigned pk[AGG_EPT];
#pragma unroll
    for (int j = 0; j < AGG_EPT; j++) {
        int e = base + j * AGG_THR + tid;
        pk[j] = 0xFFFFFFFFu;
        if (e < NNZ) {
            int r  = rows[e];
            int b  = r >> BSHIFT;                    // 9 bits
            int lp = atomicAdd(&cntS[b], 1);         // <= 4095, 12 bits
            pk[j]  = ((unsigned)b << 22) | ((unsigned)(r & (BROWS - 1)) << 12)
                   | (unsigned)lp;
        }
    }
    __syncthreads();

    // exclusive scan of cntS (SCAN_N == AGG_THR, one element per thread)
    int v = cntS[tid];
    for (int off = 1; off < SCAN_N; off <<= 1) {
        int t = 0;
        if (tid >= off) t = cntS[tid - off];
        __syncthreads();
        if (tid >= off) cntS[tid] += t;
        __syncthreads();
    }
    int excl = cntS[tid] - v;

    // reserve global runs (one atomic per non-empty bucket)
    if (tid < NBUCK && v > 0) hoff[tid] = atomicAdd(&bcur[tid * 16], v);
    __syncthreads();
    cntS[tid] = excl;
    __syncthreads();

    // phase B: stage into LDS at counting-sort position
#pragma unroll
    for (int j = 0; j < AGG_EPT; j++) {
        if (pk[j] != 0xFFFFFFFFu) {
            int e   = base + j * AGG_THR + tid;
            int b   = pk[j] >> 22;
            int rl  = (pk[j] >> 12) & (BROWS - 1);
            int lp  = pk[j] & 0xFFF;
            int idx = cntS[b] + lp;
            unsigned packed = (unsigned)cols[e] | ((unsigned)rl << 19);
            payS[idx] = make_float2(__uint_as_float(packed), vals[e]);
            bidS[idx] = (unsigned short)b;
        }
    }
    __syncthreads();

    // write-out: contiguous per-bucket runs -> coalesced, line-dense
    int total = NNZ - base; if (total > AGG_T) total = AGG_T;
    for (int i = tid; i < total; i += AGG_THR) {
        int b = bidS[i];
        int g = hoff[b] + (i - cntS[b]);
        pay[g] = payS[i];
    }
}

// pass 2: one block per coarse bucket; place edges at final CSR positions
// (random writes confined to the bucket's ~109 KB window -> L2-resident)
__global__ void place_kernel(const int*    __restrict__ row_ptr,
                             const float2* __restrict__ pay,
                             int*          __restrict__ cursor,
                             float2*       __restrict__ edges) {
    int b   = blockIdx.x;
    int beg = row_ptr[b << BSHIFT];
    int endRow = (b + 1) << BSHIFT;
    if (endRow > N_NODES) endRow = N_NODES;
    int end = row_ptr[endRow];
    for (int i = beg + threadIdx.x; i < end; i += blockDim.x) {
        float2 p = pay[i];
        unsigned u = __float_as_uint(p.x);
        int r    = (b << BSHIFT) + (int)(u >> 19);
        int pos  = atomicAdd(&cursor[r], 1);
        edges[pos] = make_float2(__uint_as_float(u & 0x7FFFFu), p.y);
    }
}

// out = bufA = concat(user, item)
__global__ void init2_kernel(const float* __restrict__ user_t,
                             const float* __restrict__ item_t,
                             float* __restrict__ out,
                             float* __restrict__ bufA) {
    int i = blockIdx.x * blockDim.x + threadIdx.x;
    const int total4 = N_NODES * EMB / 4;
    if (i >= total4) return;
    int fi   = i * 4;
    int node = fi >> 6;
    int off  = fi & 63;
    float4 v;
    if (node < N_USERS)
        v = *(const float4*)(user_t + (size_t)node * EMB + off);
    else
        v = *(const float4*)(item_t + (size_t)(node - N_USERS) * EMB + off);
    *(float4*)(out  + fi) = v;
    *(float4*)(bufA + fi) = v;
}

// SpMM: 4 rows per wave; lane = (quarter q = row, slot s = dims 4s..4s+3)
__global__ void spmm4_kernel(const int*    __restrict__ rp,
                             const float2* __restrict__ edges,
                             const float*  __restrict__ x,
                             float*        __restrict__ y,
                             float*        __restrict__ out,
                             float scale) {
    int t    = blockIdx.x * blockDim.x + threadIdx.x;
    int wid  = t >> 6;
    int lane = t & 63;
    int q    = lane >> 4;
    int s    = lane & 15;
    int row  = (wid << 2) + q;
    if (row >= N_NODES) return;
    int i   = rp[row];
    int end = rp[row + 1];
    float4 acc = make_float4(0.f, 0.f, 0.f, 0.f);
    for (; i + 1 < end; i += 2) {
        float2 e0 = edges[i];
        float2 e1 = edges[i + 1];
        float4 a = *(const float4*)(x + ((size_t)__float_as_int(e0.x) << 6) + (s << 2));
        float4 b = *(const float4*)(x + ((size_t)__float_as_int(e1.x) << 6) + (s << 2));
        acc.x += e0.y * a.x + e1.y * b.x;
        acc.y += e0.y * a.y + e1.y * b.y;
        acc.z += e0.y * a.z + e1.y * b.z;
        acc.w += e0.y * a.w + e1.y * b.w;
    }
    if (i < end) {
        float2 e0 = edges[i];
        float4 a = *(const float4*)(x + ((size_t)__float_as_int(e0.x) << 6) + (s << 2));
        acc.x += e0.y * a.x;
        acc.y += e0.y * a.y;
        acc.z += e0.y * a.z;
        acc.w += e0.y * a.w;
    }
    size_t o = ((size_t)row << 6) + (s << 2);
    *(float4*)(y + o) = acc;
    float4 ov = *(float4*)(out + o);
    ov.x = (ov.x + acc.x) * scale;
    ov.y = (ov.y + acc.y) * scale;
    ov.z = (ov.z + acc.z) * scale;
    ov.w = (ov.w + acc.w) * scale;
    *(float4*)(out + o) = ov;
}

// ===========================================================================
// Fallback atomic path (tiny ws only)
// ===========================================================================
__global__ void init_kernel(const float* __restrict__ user_t,
                            const float* __restrict__ item_t,
                            float* __restrict__ out,
                            float* __restrict__ bufA,
                            float* __restrict__ bufB) {
    int i = blockIdx.x * blockDim.x + threadIdx.x;
    const int total4 = N_NODES * EMB / 4;
    if (i >= total4) return;
    int fi   = i * 4;
    int node = fi >> 6;
    int off  = fi & 63;
    float4 v;
    if (node < N_USERS)
        v = *(const float4*)(user_t + (size_t)node * EMB + off);
    else
        v = *(const float4*)(item_t + (size_t)(node - N_USERS) * EMB + off);
    *(float4*)(out  + fi) = v;
    *(float4*)(bufA + fi) = v;
    *(float4*)(bufB + fi) = make_float4(0.f, 0.f, 0.f, 0.f);
}

__global__ void spmm_kernel(const int*   __restrict__ rows,
                            const int*   __restrict__ cols,
                            const float* __restrict__ vals,
                            const float* __restrict__ x,
                            float*       __restrict__ y) {
    int tid  = blockIdx.x * blockDim.x + threadIdx.x;
    int e    = tid >> 6;
    int lane = tid & 63;
    if (e >= NNZ) return;
    atomicAdd(&y[(size_t)rows[e] * EMB + lane], vals[e] * x[(size_t)cols[e] * EMB + lane]);
}

__global__ void acc_zero_kernel(float* __restrict__ out,
                                const float* __restrict__ src,
                                float* __restrict__ zbuf) {
    int i = blockIdx.x * blockDim.x + threadIdx.x;
    const int total4 = N_NODES * EMB / 4;
    if (i >= total4) return;
    int fi = i * 4;
    float4 o = *(float4*)(out + fi);
    float4 s = *(const float4*)(src + fi);
    o.x += s.x; o.y += s.y; o.z += s.z; o.w += s.w;
    *(float4*)(out  + fi) = o;
    *(float4*)(zbuf + fi) = make_float4(0.f, 0.f, 0.f, 0.f);
}

__global__ void final_kernel(float* __restrict__ out,
                             const float* __restrict__ src) {
    int i = blockIdx.x * blockDim.x + threadIdx.x;
    const int total4 = N_NODES * EMB / 4;
    if (i >= total4) return;
    int fi = i * 4;
    float4 o = *(float4*)(out + fi);
    float4 s = *(const float4*)(src + fi);
    o.x = (o.x + s.x) * 0.25f;
    o.y = (o.y + s.y) * 0.25f;
    o.z = (o.z + s.z) * 0.25f;
    o.w = (o.w + s.w) * 0.25f;
    *(float4*)(out + fi) = o;
}

// ===========================================================================
extern "C" void kernel_launch(void* const* d_in, const int* in_sizes, int n_in,
                              void* d_out, int out_size, void* d_ws, size_t ws_size,
                              hipStream_t stream) {
    const float* user_t = (const float*)d_in[0];
    const float* item_t = (const float*)d_in[1];
    const int*   rows   = (const int*)d_in[2];
    const int*   cols   = (const int*)d_in[3];
    const float* vals   = (const float*)d_in[4];
    float* out = (float*)d_out;

    const size_t emb_elems = (size_t)N_NODES * EMB;
    const int total4    = N_NODES * EMB / 4;
    const int ew_blocks = (total4 + 255) / 256;

    // ---- workspace layout (same footprint as before) ----
    char* p = (char*)d_ws;
    float*  bufA      = (float*)p;  p += emb_elems * 4;           // 76.8 MB
    float*  bufB      = (float*)p;  p += emb_elems * 4;           // 76.8 MB
    float2* edges     = (float2*)p; p += (size_t)NNZ * 8;         // 32 MB
    int*    row_ptr   = (int*)p;    p += (size_t)(N_NODES + 1) * 4;
    int*    cursor    = (int*)p;    p += (size_t)N_NODES * 4;
    int*    cnt       = (int*)p;    p += (size_t)N_NODES * 4;
    int*    tile_sums = (int*)p;    p += (size_t)NUM_TILES * 4;
    size_t need = (size_t)(p - (char*)d_ws);

    // aliases: pay lives in bufB (dead until first spmm); bcur lives in cnt
    // (cnt dead after scan1).
    float2* pay  = (float2*)bufB;                                 // 32 MB
    int*    bcur = cnt;                                           // 18.75 KB used

    if (ws_size >= need) {
        hipMemsetAsync(cnt, 0, (size_t)N_NODES * 4, stream);
        hist_kernel <<<(NNZ + 255) / 256, 256, 0, stream>>>(rows, cnt);
        scan1_kernel<<<NUM_TILES, SCAN_BLOCK, 0, stream>>>(cnt, row_ptr, tile_sums);
        scan2_kernel<<<1, 512, 0, stream>>>(tile_sums);
        scan3_kernel<<<(N_NODES + 255) / 256, 256, 0, stream>>>(row_ptr, tile_sums, cursor);
        binit_kernel<<<(NBUCK + 255) / 256, 256, 0, stream>>>(row_ptr, bcur);
        bucket_agg_kernel<<<AGG_BLOCKS, AGG_THR, 0, stream>>>(rows, cols, vals, bcur, pay);
        place_kernel<<<NBUCK, 1024, 0, stream>>>(row_ptr, pay, cursor, edges);

        init2_kernel<<<ew_blocks, 256, 0, stream>>>(user_t, item_t, out, bufA);

        const int spmm_blocks = (int)(((size_t)N_NODES / 4 * 64 + 255) / 256); // 18750
        spmm4_kernel<<<spmm_blocks, 256, 0, stream>>>(row_ptr, edges, bufA, bufB, out, 1.0f);
        spmm4_kernel<<<spmm_blocks, 256, 0, stream>>>(row_ptr, edges, bufB, bufA, out, 1.0f);
        spmm4_kernel<<<spmm_blocks, 256, 0, stream>>>(row_ptr, edges, bufA, bufB, out, 0.25f);
    } else {
        const int spmm_blocks = (int)(((size_t)NNZ * 64 + 255) / 256);
        init_kernel<<<ew_blocks, 256, 0, stream>>>(user_t, item_t, out, bufA, bufB);
        spmm_kernel<<<spmm_blocks, 256, 0, stream>>>(rows, cols, vals, bufA, bufB);
        acc_zero_kernel<<<ew_blocks, 256, 0, stream>>>(out, bufB, bufA);
        spmm_kernel<<<spmm_blocks, 256, 0, stream>>>(rows, cols, vals, bufB, bufA);
        acc_zero_kernel<<<ew_blocks, 256, 0, stream>>>(out, bufA, bufB);
        spmm_kernel<<<spmm_blocks, 256, 0, stream>>>(rows, cols, vals, bufA, bufB);
        final_kernel<<<ew_blocks, 256, 0, stream>>>(out, bufB);
    }
}

// Round 2
// 912.598 us; speedup vs baseline: 1.3326x; 1.1291x over previous
//
#include <hip/hip_runtime.h>

#define N_USERS 100000
#define N_ITEMS 200000
#define N_NODES (N_USERS + N_ITEMS)
#define EMB     64
#define NNZ     4000000

#define SCAN_BLOCK 256
#define SCAN_ITEMS 4
#define SCAN_TILE  (SCAN_BLOCK * SCAN_ITEMS)               // 1024
#define NUM_TILES  ((N_NODES + SCAN_TILE - 1) / SCAN_TILE) // 293

// coarse row-buckets: 1024 rows each
#define BSHIFT 10
#define BROWS  (1 << BSHIFT)                               // 1024 rows / bucket
#define NBUCK  ((N_NODES + BROWS - 1) >> BSHIFT)           // 293

// block-aggregated binning pass
#define AGG_THR    512
#define AGG_EPT    8
#define AGG_T      (AGG_THR * AGG_EPT)                     // 4096 edges / block
#define AGG_BLOCKS ((NNZ + AGG_T - 1) / AGG_T)             // 977
#define SCAN_N     512                                     // pow2 >= NBUCK

// place pass: LDS capacity per bucket (mean run 13653, std ~117 -> +14 sigma)
#define PCAP   15360
#define PITER  (PCAP / 1024)                               // 15

// ===========================================================================
// CSR build
// ===========================================================================
__global__ void hist_kernel(const int* __restrict__ rows, int* __restrict__ cnt) {
    int e = blockIdx.x * blockDim.x + threadIdx.x;
    if (e < NNZ) atomicAdd(&cnt[rows[e]], 1);
}

__global__ void scan1_kernel(const int* __restrict__ cnt,
                             int* __restrict__ excl,
                             int* __restrict__ tile_sums) {
    __shared__ int s[SCAN_BLOCK];
    int tid  = threadIdx.x;
    int base = blockIdx.x * SCAN_TILE + tid * SCAN_ITEMS;
    int v[SCAN_ITEMS];
    int sum = 0;
#pragma unroll
    for (int j = 0; j < SCAN_ITEMS; j++) {
        int idx = base + j;
        v[j] = (idx < N_NODES) ? cnt[idx] : 0;
        sum += v[j];
    }
    s[tid] = sum;
    __syncthreads();
    for (int off = 1; off < SCAN_BLOCK; off <<= 1) {
        int t = 0;
        if (tid >= off) t = s[tid - off];
        __syncthreads();
        if (tid >= off) s[tid] += t;
        __syncthreads();
    }
    int run = s[tid] - sum;
#pragma unroll
    for (int j = 0; j < SCAN_ITEMS; j++) {
        int idx = base + j;
        if (idx < N_NODES) excl[idx] = run;
        run += v[j];
    }
    if (tid == SCAN_BLOCK - 1) tile_sums[blockIdx.x] = s[tid];
}

__global__ void scan2_kernel(int* __restrict__ tile_sums) {
    __shared__ int s[512];
    int tid = threadIdx.x;
    int v = (tid < NUM_TILES) ? tile_sums[tid] : 0;
    s[tid] = v;
    __syncthreads();
    for (int off = 1; off < 512; off <<= 1) {
        int t = 0;
        if (tid >= off) t = s[tid - off];
        __syncthreads();
        if (tid >= off) s[tid] += t;
        __syncthreads();
    }
    if (tid < NUM_TILES) tile_sums[tid] = s[tid] - v;
}

__global__ void scan3_kernel(int* __restrict__ row_ptr,
                             const int* __restrict__ tile_sums,
                             int* __restrict__ cursor) {
    int i = blockIdx.x * blockDim.x + threadIdx.x;
    if (i < N_NODES) {
        int v = row_ptr[i] + tile_sums[i / SCAN_TILE];
        row_ptr[i] = v;
        cursor[i]  = v;
    }
    if (i == 0) row_ptr[N_NODES] = NNZ;
}

// bucket cursors (64B-padded) = CSR offset of bucket start
__global__ void binit_kernel(const int* __restrict__ row_ptr, int* __restrict__ bcur) {
    int b = blockIdx.x * blockDim.x + threadIdx.x;
    if (b < NBUCK) bcur[b * 16] = row_ptr[b << BSHIFT];
}

// pass 1 (block-aggregated): bin 4096 edges/block into coarse buckets via LDS
// counting-sort, reserve each bucket's run with ONE global atomic per
// (block,bucket), write runs contiguously & coalesced. rlo is packed into the
// high bits of the col field (col < 2^19, rlo 10 bits).
__global__ __launch_bounds__(AGG_THR)
void bucket_agg_kernel(const int*   __restrict__ rows,
                       const int*   __restrict__ cols,
                       const float* __restrict__ vals,
                       int*         __restrict__ bcur,
                       float2*      __restrict__ pay) {
    __shared__ int            cntS[SCAN_N];   // counts -> exclusive scan
    __shared__ int            hoff[SCAN_N];   // global run start per bucket
    __shared__ float2         payS[AGG_T];    // staged (packed col, val)
    __shared__ unsigned short bidS[AGG_T];    // bucket id per staged slot

    int tid  = threadIdx.x;
    int base = blockIdx.x * AGG_T;

    for (int i = tid; i < SCAN_N; i += AGG_THR) cntS[i] = 0;
    __syncthreads();

    // phase A: count (keep per-edge bucket/row-lo/local-pos packed in regs)
    unsigned pk[AGG_EPT];
#pragma unroll
    for (int j = 0; j < AGG_EPT; j++) {
        int e = base + j * AGG_THR + tid;
        pk[j] = 0xFFFFFFFFu;
        if (e < NNZ) {
            int r  = rows[e];
            int b  = r >> BSHIFT;                    // 9 bits
            int lp = atomicAdd(&cntS[b], 1);         // <= 4095, 12 bits
            pk[j]  = ((unsigned)b << 22) | ((unsigned)(r & (BROWS - 1)) << 12)
                   | (unsigned)lp;
        }
    }
    __syncthreads();

    // exclusive scan of cntS (SCAN_N == AGG_THR, one element per thread)
    int v = cntS[tid];
    for (int off = 1; off < SCAN_N; off <<= 1) {
        int t = 0;
        if (tid >= off) t = cntS[tid - off];
        __syncthreads();
        if (tid >= off) cntS[tid] += t;
        __syncthreads();
    }
    int excl = cntS[tid] - v;

    // reserve global runs (one atomic per non-empty bucket)
    if (tid < NBUCK && v > 0) hoff[tid] = atomicAdd(&bcur[tid * 16], v);
    __syncthreads();
    cntS[tid] = excl;
    __syncthreads();

    // phase B: stage into LDS at counting-sort position
#pragma unroll
    for (int j = 0; j < AGG_EPT; j++) {
        if (pk[j] != 0xFFFFFFFFu) {
            int e   = base + j * AGG_THR + tid;
            int b   = pk[j] >> 22;
            int rl  = (pk[j] >> 12) & (BROWS - 1);
            int lp  = pk[j] & 0xFFF;
            int idx = cntS[b] + lp;
            unsigned packed = (unsigned)cols[e] | ((unsigned)rl << 19);
            payS[idx] = make_float2(__uint_as_float(packed), vals[e]);
            bidS[idx] = (unsigned short)b;
        }
    }
    __syncthreads();

    // write-out: contiguous per-bucket runs -> coalesced, line-dense
    int total = NNZ - base; if (total > AGG_T) total = AGG_T;
    for (int i = tid; i < total; i += AGG_THR) {
        int b = bidS[i];
        int g = hoff[b] + (i - cntS[b]);
        pay[g] = payS[i];
    }
}

// pass 2: one block per coarse bucket. Counting-sort the bucket's run by row
// ENTIRELY IN LDS (120 KB payload stage + 1024 counters), then stream the
// sorted run out sequentially -> every global store is full-line coalesced.
// (Scattered 8B global stores are NOT absorbed by L2 on this chip: round-0/1
// both measured ~7x WRITE_SIZE amplification. The scatter must happen in LDS.)
__global__ __launch_bounds__(1024)
void place_kernel(const int*    __restrict__ row_ptr,
                  const float2* __restrict__ pay,
                  int*          __restrict__ cursor,
                  float2*       __restrict__ edges) {
    __shared__ float2 payS[PCAP];   // 122880 B
    __shared__ int    cntS[BROWS];  //   4096 B
    int b   = blockIdx.x;
    int tid = threadIdx.x;
    int beg = row_ptr[b << BSHIFT];
    int endRow = (b + 1) << BSHIFT;
    if (endRow > N_NODES) endRow = N_NODES;
    int end = row_ptr[endRow];
    int run = end - beg;

    if (run > PCAP) {
        // fallback (statistically unreachable: PCAP = mean + 14 sigma)
        for (int i = beg + tid; i < end; i += 1024) {
            float2 p = pay[i];
            unsigned u = __float_as_uint(p.x);
            int r   = (b << BSHIFT) + (int)(u >> 19);
            int pos = atomicAdd(&cursor[r], 1);
            edges[pos] = make_float2(__uint_as_float(u & 0x7FFFFu), p.y);
        }
        return;
    }

    cntS[tid] = 0;
    __syncthreads();

    // phase A: pull edges into registers (fully unrolled -> static indexing),
    // histogram rows; atomic return value = within-row slot.
    unsigned eu[PITER]; float ev[PITER]; int elp[PITER];
#pragma unroll
    for (int j = 0; j < PITER; j++) {
        int i = beg + j * 1024 + tid;
        eu[j] = 0xFFFFFFFFu;
        if (i < end) {
            float2 p = pay[i];
            unsigned u = __float_as_uint(p.x);
            eu[j] = u;
            ev[j] = p.y;
            elp[j] = atomicAdd(&cntS[(u >> 19) & (BROWS - 1)], 1);
        }
    }
    __syncthreads();

    // inclusive scan of the 1024 row-counts; exclusive(r) = cntS[r-1]
    for (int off = 1; off < BROWS; off <<= 1) {
        int t = 0;
        if (tid >= off) t = cntS[tid - off];
        __syncthreads();
        if (tid >= off) cntS[tid] += t;
        __syncthreads();
    }

    // phase B: scatter into LDS at final sorted position
#pragma unroll
    for (int j = 0; j < PITER; j++) {
        if (eu[j] != 0xFFFFFFFFu) {
            int r    = (int)((eu[j] >> 19) & (BROWS - 1));
            int base = (r == 0) ? 0 : cntS[r - 1];
            payS[base + elp[j]] = make_float2(__uint_as_float(eu[j] & 0x7FFFFu), ev[j]);
        }
    }
    __syncthreads();

    // phase C: stream out sequentially — full-line coalesced stores
    for (int i = tid; i < run; i += 1024) {
        edges[beg + i] = payS[i];
    }
}

// out = bufA = concat(user, item)
__global__ void init2_kernel(const float* __restrict__ user_t,
                             const float* __restrict__ item_t,
                             float* __restrict__ out,
                             float* __restrict__ bufA) {
    int i = blockIdx.x * blockDim.x + threadIdx.x;
    const int total4 = N_NODES * EMB / 4;
    if (i >= total4) return;
    int fi   = i * 4;
    int node = fi >> 6;
    int off  = fi & 63;
    float4 v;
    if (node < N_USERS)
        v = *(const float4*)(user_t + (size_t)node * EMB + off);
    else
        v = *(const float4*)(item_t + (size_t)(node - N_USERS) * EMB + off);
    *(float4*)(out  + fi) = v;
    *(float4*)(bufA + fi) = v;
}

// SpMM: 4 rows per wave; lane = (quarter q = row, slot s = dims 4s..4s+3)
__global__ void spmm4_kernel(const int*    __restrict__ rp,
                             const float2* __restrict__ edges,
                             const float*  __restrict__ x,
                             float*        __restrict__ y,
                             float*        __restrict__ out,
                             float scale) {
    int t    = blockIdx.x * blockDim.x + threadIdx.x;
    int wid  = t >> 6;
    int lane = t & 63;
    int q    = lane >> 4;
    int s    = lane & 15;
    int row  = (wid << 2) + q;
    if (row >= N_NODES) return;
    int i   = rp[row];
    int end = rp[row + 1];
    float4 acc = make_float4(0.f, 0.f, 0.f, 0.f);
    for (; i + 1 < end; i += 2) {
        float2 e0 = edges[i];
        float2 e1 = edges[i + 1];
        float4 a = *(const float4*)(x + ((size_t)__float_as_int(e0.x) << 6) + (s << 2));
        float4 b = *(const float4*)(x + ((size_t)__float_as_int(e1.x) << 6) + (s << 2));
        acc.x += e0.y * a.x + e1.y * b.x;
        acc.y += e0.y * a.y + e1.y * b.y;
        acc.z += e0.y * a.z + e1.y * b.z;
        acc.w += e0.y * a.w + e1.y * b.w;
    }
    if (i < end) {
        float2 e0 = edges[i];
        float4 a = *(const float4*)(x + ((size_t)__float_as_int(e0.x) << 6) + (s << 2));
        acc.x += e0.y * a.x;
        acc.y += e0.y * a.y;
        acc.z += e0.y * a.z;
        acc.w += e0.y * a.w;
    }
    size_t o = ((size_t)row << 6) + (s << 2);
    *(float4*)(y + o) = acc;
    float4 ov = *(float4*)(out + o);
    ov.x = (ov.x + acc.x) * scale;
    ov.y = (ov.y + acc.y) * scale;
    ov.z = (ov.z + acc.z) * scale;
    ov.w = (ov.w + acc.w) * scale;
    *(float4*)(out + o) = ov;
}

// ===========================================================================
// Fallback atomic path (tiny ws only)
// ===========================================================================
__global__ void init_kernel(const float* __restrict__ user_t,
                            const float* __restrict__ item_t,
                            float* __restrict__ out,
                            float* __restrict__ bufA,
                            float* __restrict__ bufB) {
    int i = blockIdx.x * blockDim.x + threadIdx.x;
    const int total4 = N_NODES * EMB / 4;
    if (i >= total4) return;
    int fi   = i * 4;
    int node = fi >> 6;
    int off  = fi & 63;
    float4 v;
    if (node < N_USERS)
        v = *(const float4*)(user_t + (size_t)node * EMB + off);
    else
        v = *(const float4*)(item_t + (size_t)(node - N_USERS) * EMB + off);
    *(float4*)(out  + fi) = v;
    *(float4*)(bufA + fi) = v;
    *(float4*)(bufB + fi) = make_float4(0.f, 0.f, 0.f, 0.f);
}

__global__ void spmm_kernel(const int*   __restrict__ rows,
                            const int*   __restrict__ cols,
                            const float* __restrict__ vals,
                            const float* __restrict__ x,
                            float*       __restrict__ y) {
    int tid  = blockIdx.x * blockDim.x + threadIdx.x;
    int e    = tid >> 6;
    int lane = tid & 63;
    if (e >= NNZ) return;
    atomicAdd(&y[(size_t)rows[e] * EMB + lane], vals[e] * x[(size_t)cols[e] * EMB + lane]);
}

__global__ void acc_zero_kernel(float* __restrict__ out,
                                const float* __restrict__ src,
                                float* __restrict__ zbuf) {
    int i = blockIdx.x * blockDim.x + threadIdx.x;
    const int total4 = N_NODES * EMB / 4;
    if (i >= total4) return;
    int fi = i * 4;
    float4 o = *(float4*)(out + fi);
    float4 s = *(const float4*)(src + fi);
    o.x += s.x; o.y += s.y; o.z += s.z; o.w += s.w;
    *(float4*)(out  + fi) = o;
    *(float4*)(zbuf + fi) = make_float4(0.f, 0.f, 0.f, 0.f);
}

__global__ void final_kernel(float* __restrict__ out,
                             const float* __restrict__ src) {
    int i = blockIdx.x * blockDim.x + threadIdx.x;
    const int total4 = N_NODES * EMB / 4;
    if (i >= total4) return;
    int fi = i * 4;
    float4 o = *(float4*)(out + fi);
    float4 s = *(const float4*)(src + fi);
    o.x = (o.x + s.x) * 0.25f;
    o.y = (o.y + s.y) * 0.25f;
    o.z = (o.z + s.z) * 0.25f;
    o.w = (o.w + s.w) * 0.25f;
    *(float4*)(out + fi) = o;
}

// ===========================================================================
extern "C" void kernel_launch(void* const* d_in, const int* in_sizes, int n_in,
                              void* d_out, int out_size, void* d_ws, size_t ws_size,
                              hipStream_t stream) {
    const float* user_t = (const float*)d_in[0];
    const float* item_t = (const float*)d_in[1];
    const int*   rows   = (const int*)d_in[2];
    const int*   cols   = (const int*)d_in[3];
    const float* vals   = (const float*)d_in[4];
    float* out = (float*)d_out;

    const size_t emb_elems = (size_t)N_NODES * EMB;
    const int total4    = N_NODES * EMB / 4;
    const int ew_blocks = (total4 + 255) / 256;

    // ---- workspace layout (same footprint as before) ----
    char* p = (char*)d_ws;
    float*  bufA      = (float*)p;  p += emb_elems * 4;           // 76.8 MB
    float*  bufB      = (float*)p;  p += emb_elems * 4;           // 76.8 MB
    float2* edges     = (float2*)p; p += (size_t)NNZ * 8;         // 32 MB
    int*    row_ptr   = (int*)p;    p += (size_t)(N_NODES + 1) * 4;
    int*    cursor    = (int*)p;    p += (size_t)N_NODES * 4;
    int*    cnt       = (int*)p;    p += (size_t)N_NODES * 4;
    int*    tile_sums = (int*)p;    p += (size_t)NUM_TILES * 4;
    size_t need = (size_t)(p - (char*)d_ws);

    // aliases: pay lives in bufB (dead until first spmm); bcur lives in cnt
    // (cnt dead after scan1).
    float2* pay  = (float2*)bufB;                                 // 32 MB
    int*    bcur = cnt;                                           // 18.75 KB used

    if (ws_size >= need) {
        hipMemsetAsync(cnt, 0, (size_t)N_NODES * 4, stream);
        hist_kernel <<<(NNZ + 255) / 256, 256, 0, stream>>>(rows, cnt);
        scan1_kernel<<<NUM_TILES, SCAN_BLOCK, 0, stream>>>(cnt, row_ptr, tile_sums);
        scan2_kernel<<<1, 512, 0, stream>>>(tile_sums);
        scan3_kernel<<<(N_NODES + 255) / 256, 256, 0, stream>>>(row_ptr, tile_sums, cursor);
        binit_kernel<<<(NBUCK + 255) / 256, 256, 0, stream>>>(row_ptr, bcur);
        bucket_agg_kernel<<<AGG_BLOCKS, AGG_THR, 0, stream>>>(rows, cols, vals, bcur, pay);
        place_kernel<<<NBUCK, 1024, 0, stream>>>(row_ptr, pay, cursor, edges);

        init2_kernel<<<ew_blocks, 256, 0, stream>>>(user_t, item_t, out, bufA);

        const int spmm_blocks = (int)(((size_t)N_NODES / 4 * 64 + 255) / 256); // 18750
        spmm4_kernel<<<spmm_blocks, 256, 0, stream>>>(row_ptr, edges, bufA, bufB, out, 1.0f);
        spmm4_kernel<<<spmm_blocks, 256, 0, stream>>>(row_ptr, edges, bufB, bufA, out, 1.0f);
        spmm4_kernel<<<spmm_blocks, 256, 0, stream>>>(row_ptr, edges, bufA, bufB, out, 0.25f);
    } else {
        const int spmm_blocks = (int)(((size_t)NNZ * 64 + 255) / 256);
        init_kernel<<<ew_blocks, 256, 0, stream>>>(user_t, item_t, out, bufA, bufB);
        spmm_kernel<<<spmm_blocks, 256, 0, stream>>>(rows, cols, vals, bufA, bufB);
        acc_zero_kernel<<<ew_blocks, 256, 0, stream>>>(out, bufB, bufA);
        spmm_kernel<<<spmm_blocks, 256, 0, stream>>>(rows, cols, vals, bufB, bufA);
        acc_zero_kernel<<<ew_blocks, 256, 0, stream>>>(out, bufA, bufB);
        spmm_kernel<<<spmm_blocks, 256, 0, stream>>>(rows, cols, vals, bufA, bufB);
        final_kernel<<<ew_blocks, 256, 0, stream>>>(out, bufB);
    }
}